// Round 9
// baseline (280.464 us; speedup 1.0000x reference)
//
#include <hip/hip_runtime.h>
#include <hip/hip_bf16.h>

using bf16 = __hip_bfloat16;
#define DEV __device__ __forceinline__

typedef __attribute__((ext_vector_type(8))) short short8;
typedef __attribute__((ext_vector_type(8))) unsigned short ushort8;
typedef __attribute__((ext_vector_type(4))) float f32x4;

constexpr int Bb = 2, DD = 8, HH = 16, WW = 16;
constexpr int C = 384, DI = 384, DS = 16, RR = 24;
constexpr int L = DD * HH * WW;       // 2048
constexpr int M = Bb * L;             // 4096

DEV bf16 f2b(float v) { return __float2bfloat16(v); }
DEV unsigned short f2bu(float v) {
    bf16 t = __float2bfloat16(v);
    unsigned short u; __builtin_memcpy(&u, &t, 2); return u;
}
DEV float braw(unsigned short u) {
    unsigned int x = ((unsigned int)u) << 16;
    float f; __builtin_memcpy(&f, &x, 4); return f;
}
DEV bool isbf(const unsigned short* g1p) { return g1p[0] == 0x3F80; }

typedef const __attribute__((address_space(1))) unsigned int* gaddr_t;
typedef __attribute__((address_space(3))) unsigned int* laddr_t;
DEV void gload_lds16(const void* g, void* l) {
    __builtin_amdgcn_global_load_lds((gaddr_t)g, (laddr_t)l, 16, 0, 0);
}

DEV float wred64(float v) {
    #pragma unroll
    for (int off = 32; off > 0; off >>= 1) v += __shfl_xor(v, off, 64);
    return v;
}
DEV float siluf(float x) { return x / (1.0f + __expf(-x)); }
DEV float softplusf(float x) { return (x > 15.0f) ? x : log1pf(__expf(x)); }
DEV float gelu_tanh(float x) {
    const float k0 = 0.7978845608028654f;
    float u = k0 * (x + 0.044715f * x * x * x);
    float e = __expf(2.0f * u);
    float t = 1.0f - 2.0f / (e + 1.0f);
    return 0.5f * x * (1.0f + t);
}

// --------- merged prep: 4 weight transposes + 17 small cvts ---------------
struct PrepTab {
    const void* tsrc[4];
    unsigned short* tdst[4];
    int tK[4], tN[4];
    const void* csrc[17];
    float* cdst[17];
    int coff[18];
};
__global__ __launch_bounds__(256) void prep_k(PrepTab t,
                                              const unsigned short* __restrict__ g1p,
                                              int ctotal) {
    bool fl = isbf(g1p);
    int z = blockIdx.z;
    if (z < 4) {
        __shared__ unsigned short tt[32][33];
        int N = t.tN[z], K = t.tK[z];
        int n0 = blockIdx.x * 32, k0 = blockIdx.y * 32;
        if (n0 >= N || k0 >= K) return;
        const void* src = t.tsrc[z];
        unsigned short* dst = t.tdst[z];
        int tx = threadIdx.x & 31, ty = threadIdx.x >> 5;
        #pragma unroll
        for (int i = 0; i < 4; i++) {
            int k = k0 + ty + i * 8;
            unsigned short u;
            if (fl) u = ((const unsigned short*)src)[(size_t)k * N + n0 + tx];
            else    u = f2bu(((const float*)src)[(size_t)k * N + n0 + tx]);
            tt[ty + i * 8][tx] = u;
        }
        __syncthreads();
        #pragma unroll
        for (int i = 0; i < 4; i++) {
            int n = n0 + ty + i * 8;
            dst[(size_t)n * K + k0 + tx] = tt[tx][ty + i * 8];
        }
    } else {
        int i = (blockIdx.y * 24 + blockIdx.x) * 256 + threadIdx.x;
        if (i >= ctotal) return;
        int seg = 0;
        #pragma unroll
        for (int k = 1; k < 18; k++) seg += (i >= t.coff[k]) ? 1 : 0;
        int j = i - t.coff[seg];
        const void* s = t.csrc[seg];
        float v = fl ? braw(((const unsigned short*)s)[j]) : ((const float*)s)[j];
        t.cdst[seg][j] = v;
    }
}

enum { EPI_XZT = 0, EPI_OUT = 1, EPI_GELU = 2, EPI_FINAL = 3 };

// ------ GEMM with fused LayerNorm on A: LN(A)[M][384] x Bt[N][384] --------
// ARAW: A dtype per flag (raw input); else fp32.
template <int N, int TN, int EPI, bool ARAW>
__global__ __launch_bounds__(256) void lngemm_k(const void* __restrict__ Ar,
                                                const float* __restrict__ g,
                                                const float* __restrict__ b,
                                                const unsigned short* __restrict__ Bt,
                                                const float* __restrict__ bias,
                                                float* __restrict__ o0,
                                                float* __restrict__ o1,
                                                void* __restrict__ obf,
                                                const unsigned short* __restrict__ g1p) {
    __shared__ unsigned short Asb[128 * 32];
    __shared__ unsigned short Bsb[TN * 32];
    __shared__ float mean_s[128], rstd_s[128];
    __shared__ float gb[768];
    constexpr int MT = (TN == 128) ? 4 : 2;
    int tid = threadIdx.x;
    int m0 = blockIdx.x * 128, n0 = blockIdx.y * TN;
    int wid = tid >> 6, lane = tid & 63;
    bool fl = ARAW ? isbf(g1p) : false;
    for (int i = tid; i < 384; i += 256) { gb[i] = g[i]; gb[384 + i] = b[i]; }
    // ---- stats: wave wid owns rows [32*wid, 32*wid+32) ----
    for (int r = 0; r < 32; r++) {
        int row = m0 + wid * 32 + r;
        float v[6];
        #pragma unroll
        for (int j = 0; j < 6; j++) {
            size_t idx = (size_t)row * 384 + lane + 64 * j;
            if (ARAW && fl) v[j] = braw(((const unsigned short*)Ar)[idx]);
            else            v[j] = ((const float*)Ar)[idx];
        }
        float s = 0.f;
        #pragma unroll
        for (int j = 0; j < 6; j++) s += v[j];
        s = wred64(s);
        float mean = s * (1.0f / 384.0f);
        float q = 0.f;
        #pragma unroll
        for (int j = 0; j < 6; j++) { float d = v[j] - mean; q += d * d; }
        q = wred64(q);
        if (lane == 0) {
            mean_s[wid * 32 + r] = mean;
            rstd_s[wid * 32 + r] = rsqrtf(q * (1.0f / 384.0f) + 1e-6f);
        }
    }
    int wm = (TN == 128) ? (wid >> 1) * 64 : wid * 32;
    int wn = (TN == 128) ? (wid & 1) * 64 : 0;
    int quad = lane >> 4, l15 = lane & 15;
    f32x4 acc[MT][4] = {};
    int srow = tid >> 2, sseg = (tid & 3) * 8;
    for (int k0 = 0; k0 < 384; k0 += 32) {
        __syncthreads();
        #pragma unroll
        for (int half = 0; half < 2; half++) {
            int r = srow + half * 64;
            size_t off = (size_t)(m0 + r) * 384 + k0 + sseg;
            float vals[8];
            if (ARAW && fl) {
                uint4 u = *(const uint4*)((const unsigned short*)Ar + off);
                unsigned short us[8]; __builtin_memcpy(us, &u, 16);
                #pragma unroll
                for (int j = 0; j < 8; j++) vals[j] = braw(us[j]);
            } else {
                float4 f0 = *(const float4*)((const float*)Ar + off);
                float4 f1 = *(const float4*)((const float*)Ar + off + 4);
                vals[0] = f0.x; vals[1] = f0.y; vals[2] = f0.z; vals[3] = f0.w;
                vals[4] = f1.x; vals[5] = f1.y; vals[6] = f1.z; vals[7] = f1.w;
            }
            float mn = mean_s[r], rs = rstd_s[r];
            unsigned short ou[8];
            #pragma unroll
            for (int j = 0; j < 8; j++)
                ou[j] = f2bu((vals[j] - mn) * rs * gb[k0 + sseg + j] + gb[384 + k0 + sseg + j]);
            uint4 pk; __builtin_memcpy(&pk, ou, 16);
            *(uint4*)&Asb[r * 32 + sseg] = pk;
        }
        gload_lds16(Bt + (size_t)(n0 + srow) * 384 + k0 + sseg, &Bsb[srow * 32 + sseg]);
        if constexpr (TN == 128)
            gload_lds16(Bt + (size_t)(n0 + 64 + srow) * 384 + k0 + sseg,
                        &Bsb[(64 + srow) * 32 + sseg]);
        __syncthreads();
        short8 af[MT], bfr[4];
        #pragma unroll
        for (int mt = 0; mt < MT; mt++)
            af[mt] = *(const short8*)&Asb[(wm + mt * 16 + l15) * 32 + quad * 8];
        #pragma unroll
        for (int nt = 0; nt < 4; nt++)
            bfr[nt] = *(const short8*)&Bsb[(wn + nt * 16 + l15) * 32 + quad * 8];
        #pragma unroll
        for (int mt = 0; mt < MT; mt++)
            #pragma unroll
            for (int nt = 0; nt < 4; nt++)
                acc[mt][nt] = __builtin_amdgcn_mfma_f32_16x16x32_bf16(
                    af[mt], bfr[nt], acc[mt][nt], 0, 0, 0);
    }
    #pragma unroll
    for (int mt = 0; mt < MT; mt++) {
        #pragma unroll
        for (int nt = 0; nt < 4; nt++) {
            int n = n0 + wn + nt * 16 + l15;
            int mb = m0 + wm + mt * 16 + quad * 4;
            float bi = bias[n];
            if constexpr (EPI == EPI_XZT) {
                f32x4 v = acc[mt][nt];
                v[0] += bi; v[1] += bi; v[2] += bi; v[3] += bi;
                float* dst = (n < 384) ? (o0 + (size_t)n * M + mb)
                                       : (o1 + (size_t)(n - 384) * M + mb);
                *(f32x4*)dst = v;
            } else {  // EPI_GELU
                #pragma unroll
                for (int r = 0; r < 4; r++) {
                    int m = mb + r;
                    float v = acc[mt][nt][r] + bi;
                    ((bf16*)obf)[(size_t)m * 384 + n] = f2b(gelu_tanh(v));
                }
            }
        }
    }
}

// --------------- plain MFMA GEMM (A already bf16 row-major) ---------------
template <int N, int TN, int EPI>
__global__ __launch_bounds__(256) void gemm_mfma(const bf16* __restrict__ A,
                                                 const unsigned short* __restrict__ Bt,
                                                 const float* __restrict__ bias,
                                                 float* __restrict__ o0,
                                                 const float* __restrict__ auxf,
                                                 const void* __restrict__ auxraw,
                                                 void* __restrict__ obf,
                                                 const unsigned short* __restrict__ g1p) {
    __shared__ unsigned short Asb[128 * 32];
    __shared__ unsigned short Bsb[TN * 32];
    constexpr int MT = (TN == 128) ? 4 : 2;
    int tid = threadIdx.x;
    int m0 = blockIdx.x * 128, n0 = blockIdx.y * TN;
    int wid = tid >> 6, lane = tid & 63;
    int wm = (TN == 128) ? (wid >> 1) * 64 : wid * 32;
    int wn = (TN == 128) ? (wid & 1) * 64 : 0;
    int quad = lane >> 4, l15 = lane & 15;
    f32x4 acc[MT][4] = {};
    int srow = tid >> 2, sseg = (tid & 3) * 8;
    const unsigned short* Au = (const unsigned short*)A;
    for (int k0 = 0; k0 < 384; k0 += 32) {
        __syncthreads();
        gload_lds16(Au + (size_t)(m0 + srow) * 384 + k0 + sseg, &Asb[srow * 32 + sseg]);
        gload_lds16(Au + (size_t)(m0 + 64 + srow) * 384 + k0 + sseg,
                    &Asb[(64 + srow) * 32 + sseg]);
        gload_lds16(Bt + (size_t)(n0 + srow) * 384 + k0 + sseg, &Bsb[srow * 32 + sseg]);
        if constexpr (TN == 128)
            gload_lds16(Bt + (size_t)(n0 + 64 + srow) * 384 + k0 + sseg,
                        &Bsb[(64 + srow) * 32 + sseg]);
        __syncthreads();
        short8 af[MT], bfr[4];
        #pragma unroll
        for (int mt = 0; mt < MT; mt++)
            af[mt] = *(const short8*)&Asb[(wm + mt * 16 + l15) * 32 + quad * 8];
        #pragma unroll
        for (int nt = 0; nt < 4; nt++)
            bfr[nt] = *(const short8*)&Bsb[(wn + nt * 16 + l15) * 32 + quad * 8];
        #pragma unroll
        for (int mt = 0; mt < MT; mt++)
            #pragma unroll
            for (int nt = 0; nt < 4; nt++)
                acc[mt][nt] = __builtin_amdgcn_mfma_f32_16x16x32_bf16(
                    af[mt], bfr[nt], acc[mt][nt], 0, 0, 0);
    }
    bool fl = isbf(g1p);
    #pragma unroll
    for (int mt = 0; mt < MT; mt++) {
        #pragma unroll
        for (int nt = 0; nt < 4; nt++) {
            int n = n0 + wn + nt * 16 + l15;
            int mb = m0 + wm + mt * 16 + quad * 4;
            float bi = bias[n];
            #pragma unroll
            for (int r = 0; r < 4; r++) {
                int m = mb + r;
                float v = acc[mt][nt][r] + bi;
                if constexpr (EPI == EPI_OUT) {
                    float av;
                    if (fl) av = braw(((const unsigned short*)auxraw)[(size_t)m * 384 + n]);
                    else    av = ((const float*)auxraw)[(size_t)m * 384 + n];
                    o0[(size_t)m * 384 + n] = v + av;
                } else {  // EPI_FINAL
                    float rr = v + auxf[(size_t)m * 384 + n];
                    if (fl) ((bf16*)obf)[(size_t)m * 384 + n] = f2b(rr);
                    else    ((float*)obf)[(size_t)m * 384 + n] = rr;
                }
            }
        }
    }
}

// --------- depthwise 3x3x3 conv + SiLU, 4 outputs per thread --------------
__global__ __launch_bounds__(256) void convT_k(const float* __restrict__ xT,
                                               const float* __restrict__ cw,
                                               const float* __restrict__ cb,
                                               float* __restrict__ xinT) {
    int c = blockIdx.y;
    int m0 = (blockIdx.x * 256 + threadIdx.x) * 4;
    int l = m0 & (L - 1);
    int d = l >> 8, h = (l >> 4) & 15, w0 = l & 15;
    const float* xc = xT + (size_t)c * M;
    const float* wc = cw + c * 27;
    float bias = cb[c];
    float acc[4] = {bias, bias, bias, bias};
    #pragma unroll
    for (int kd = -1; kd <= 1; kd++) {
        int dd = d + kd; if ((unsigned)dd >= 8u) continue;
        #pragma unroll
        for (int kh = -1; kh <= 1; kh++) {
            int hh = h + kh; if ((unsigned)hh >= 16u) continue;
            int mm = m0 + kd * 256 + kh * 16;
            float vv[6];
            vv[0] = (w0 == 0) ? 0.f : xc[mm - 1];
            float4 v14 = *(const float4*)(xc + mm);
            vv[1] = v14.x; vv[2] = v14.y; vv[3] = v14.z; vv[4] = v14.w;
            vv[5] = (w0 == 12) ? 0.f : xc[mm + 4];
            const float* wk = wc + (kd + 1) * 9 + (kh + 1) * 3;
            float wa = wk[0], wb = wk[1], wcc = wk[2];
            #pragma unroll
            for (int j = 0; j < 4; j++)
                acc[j] = fmaf(vv[j], wa, fmaf(vv[j + 1], wb, fmaf(vv[j + 2], wcc, acc[j])));
        }
    }
    float4 o = make_float4(siluf(acc[0]), siluf(acc[1]), siluf(acc[2]), siluf(acc[3]));
    *(float4*)(xinT + (size_t)c * M + m0) = o;
}

// ---- dbc split-K: partials part[kc][56][M] -------------------------------
__global__ __launch_bounds__(256) void dbc2_k(const float* __restrict__ xinT,
                                              const float* __restrict__ Wx,
                                              float* __restrict__ part) {
    __shared__ float As[16][64];
    __shared__ float Ws[16 * 56];
    int tid = threadIdx.x;
    int m0 = blockIdx.x * 64;
    int kc = blockIdx.y;
    int tm = tid & 63, grp = tid >> 6;
    int kk = tid >> 4, mc = (tid & 15) * 4;
    float acc[14] = {};
    for (int k0 = kc * 64; k0 < kc * 64 + 64; k0 += 16) {
        float4 av = *(const float4*)(xinT + (size_t)(k0 + kk) * M + m0 + mc);
        __syncthreads();
        *(float4*)&As[kk][mc] = av;
        for (int idx = tid; idx < 16 * 56; idx += 256)
            Ws[idx] = Wx[k0 * 56 + idx];
        __syncthreads();
        #pragma unroll
        for (int k = 0; k < 16; k++) {
            float a = As[k][tm];
            #pragma unroll
            for (int jj = 0; jj < 14; jj++)
                acc[jj] = fmaf(a, Ws[k * 56 + grp * 14 + jj], acc[jj]);
        }
    }
    int m = m0 + tm;
    #pragma unroll
    for (int jj = 0; jj < 14; jj++) {
        int col = grp * 14 + jj;
        part[((size_t)kc * 56 + col) * M + m] = acc[jj];
    }
}

// ---- fused: reduce partials + write B/C + dtT = softplus(dtr @ Wdt) ------
// grid (M/64, 6), block 256. Block y covers n in [64y, 64y+64).
__global__ __launch_bounds__(256) void dbcfin_k(const float* __restrict__ part,
                                                const float* __restrict__ Wdt,
                                                const float* __restrict__ bdt,
                                                float* __restrict__ dtT,
                                                unsigned short* __restrict__ Brow,
                                                unsigned short* __restrict__ Crow) {
    __shared__ float dtr[24][64];
    int tid = threadIdx.x;
    int m0 = blockIdx.x * 64;
    int ng = blockIdx.y;
    for (int i = tid; i < 24 * 64; i += 256) {
        int col = i >> 6, mm = i & 63;
        float s = 0.f;
        #pragma unroll
        for (int kc = 0; kc < 6; kc++)
            s += part[((size_t)kc * 56 + col) * M + m0 + mm];
        dtr[col][mm] = s;
    }
    if (ng == 0) {
        for (int i = tid; i < 32 * 64; i += 256) {
            int col = 24 + (i >> 6), mm = i & 63;
            float s = 0.f;
            #pragma unroll
            for (int kc = 0; kc < 6; kc++)
                s += part[((size_t)kc * 56 + col) * M + m0 + mm];
            int m = m0 + mm;
            if (col < 40) Brow[(size_t)m * 16 + col - 24] = f2bu(s);
            else          Crow[(size_t)m * 16 + col - 40] = f2bu(s);
        }
    }
    __syncthreads();
    int mm = tid & 63, nq = tid >> 6;
    #pragma unroll 4
    for (int nj = 0; nj < 16; nj++) {
        int n = ng * 64 + nq * 16 + nj;
        float acc = bdt[n];
        #pragma unroll
        for (int j = 0; j < 24; j++)
            acc = fmaf(dtr[j][mm], Wdt[j * 384 + n], acc);
        dtT[(size_t)n * M + m0 + mm] = softplusf(acc);
    }
}

// ------------- scan4: LDS-staged, padded, register-state scan -------------
__global__ __launch_bounds__(128) void scan4_k(const float* __restrict__ dtT,
                                               const float* __restrict__ xinT,
                                               const unsigned short* __restrict__ Brow,
                                               const unsigned short* __restrict__ Crow,
                                               const float* __restrict__ alog,
                                               const float* __restrict__ dsk,
                                               float* __restrict__ yT) {
    __shared__ float dt_s[2112], x_s[2112];
    __shared__ float ypart[2 * 2112];
    int bi = blockIdx.x;
    int b = bi / DI, d = bi % DI;
    int wave = threadIdx.x >> 6, lane = threadIdx.x & 63;
    int s0 = wave * 8;
    float Aneg[8];
    #pragma unroll
    for (int ss = 0; ss < 8; ss++) Aneg[ss] = -__expf(alog[d * DS + s0 + ss]);
    const float* dtp = dtT + (size_t)d * M + b * L;
    const float* xp  = xinT + (size_t)d * M + b * L;
    #pragma unroll
    for (int i = 0; i < 4; i++) {
        int t4 = (threadIdx.x + i * 128) * 4;
        float4 dv = *(const float4*)(dtp + t4);
        float4 xv = *(const float4*)(xp + t4);
        int base = t4 + (t4 >> 5);
        dt_s[base + 0] = dv.x; dt_s[base + 1] = dv.y;
        dt_s[base + 2] = dv.z; dt_s[base + 3] = dv.w;
        x_s[base + 0] = xv.x; x_s[base + 1] = xv.y;
        x_s[base + 2] = xv.z; x_s[base + 3] = xv.w;
    }
    __syncthreads();
    const unsigned short* Bp = Brow + ((size_t)b * L) * 16 + s0;
    const unsigned short* Cp = Crow + ((size_t)b * L) * 16 + s0;
    int tbase = lane * 32;
    int pbase = lane * 33;
    float Ap[8], Bg[8];
    #pragma unroll
    for (int ss = 0; ss < 8; ss++) { Ap[ss] = 1.f; Bg[ss] = 0.f; }
    #pragma unroll 4
    for (int j = 0; j < 32; j++) {
        float dtv = dt_s[pbase + j];
        float dxv = dtv * x_s[pbase + j];
        ushort8 bu = *(const ushort8*)(Bp + (size_t)(tbase + j) * 16);
        #pragma unroll
        for (int ss = 0; ss < 8; ss++) {
            float dA = __expf(dtv * Aneg[ss]);
            Bg[ss] = fmaf(dA, Bg[ss], dxv * braw(bu[ss]));
            Ap[ss] *= dA;
        }
    }
    float carry[8];
    #pragma unroll
    for (int ss = 0; ss < 8; ss++) {
        float a = Ap[ss], bb = Bg[ss];
        #pragma unroll
        for (int off = 1; off < 64; off <<= 1) {
            float ap = __shfl_up(a, off, 64);
            float bp = __shfl_up(bb, off, 64);
            if (lane >= off) { bb = fmaf(a, bp, bb); a *= ap; }
        }
        float c = __shfl_up(bb, 1, 64);
        carry[ss] = (lane == 0) ? 0.f : c;
    }
    float* ypw = ypart + wave * 2112;
    float h[8];
    #pragma unroll
    for (int ss = 0; ss < 8; ss++) h[ss] = carry[ss];
    #pragma unroll 4
    for (int j = 0; j < 32; j++) {
        float dtv = dt_s[pbase + j];
        float dxv = dtv * x_s[pbase + j];
        size_t toff = (size_t)(tbase + j) * 16;
        ushort8 bu = *(const ushort8*)(Bp + toff);
        ushort8 cu = *(const ushort8*)(Cp + toff);
        float acc = 0.f;
        #pragma unroll
        for (int ss = 0; ss < 8; ss++) {
            float dA = __expf(dtv * Aneg[ss]);
            h[ss] = fmaf(dA, h[ss], dxv * braw(bu[ss]));
            acc = fmaf(h[ss], braw(cu[ss]), acc);
        }
        ypw[pbase + j] = acc;
    }
    __syncthreads();
    float Dv = dsk[d];
    float* yp = yT + (size_t)d * M + b * L;
    #pragma unroll
    for (int i = 0; i < 16; i++) {
        int t = threadIdx.x + 128 * i;
        int ti = t + (t >> 5);
        yp[t] = fmaf(x_s[ti], Dv, ypart[ti] + ypart[2112 + ti]);
    }
}

// ---- yact(row bf16) = LN_over_d(yT) * silu(zT), coalesced two-pass -------
__global__ __launch_bounds__(256) void lnmulT_k(const float* __restrict__ yT,
                                                const float* __restrict__ zT,
                                                const float* __restrict__ g,
                                                const float* __restrict__ b,
                                                unsigned short* __restrict__ yact) {
    __shared__ float rs1[8][32], rs2[8][32];
    __shared__ float meanb[32], rstdb[32];
    __shared__ unsigned short tile[32][392];
    int moff = threadIdx.x & 31;
    int dsub = threadIdx.x >> 5;
    int m0 = blockIdx.x * 32;
    size_t mg = m0 + moff;
    float s1 = 0.f, s2 = 0.f;
    #pragma unroll 8
    for (int j = 0; j < 48; j++) {
        int d = dsub + 8 * j;
        float v = yT[(size_t)d * M + mg];
        s1 += v; s2 += v * v;
    }
    rs1[dsub][moff] = s1;
    rs2[dsub][moff] = s2;
    __syncthreads();
    if (threadIdx.x < 32) {
        float a1 = 0.f, a2 = 0.f;
        #pragma unroll
        for (int ss = 0; ss < 8; ss++) { a1 += rs1[ss][threadIdx.x]; a2 += rs2[ss][threadIdx.x]; }
        float mean = a1 * (1.0f / DI);
        float var = a2 * (1.0f / DI) - mean * mean;
        meanb[threadIdx.x] = mean;
        rstdb[threadIdx.x] = rsqrtf(var + 1e-6f);
    }
    __syncthreads();
    float mean = meanb[moff], rstd = rstdb[moff];
    #pragma unroll 8
    for (int j = 0; j < 48; j++) {
        int d = dsub + 8 * j;
        float v = yT[(size_t)d * M + mg];
        float ln = (v - mean) * rstd * g[d] + b[d];
        float zv = zT[(size_t)d * M + mg];
        tile[moff][d] = f2bu(ln * siluf(zv));
    }
    __syncthreads();
    #pragma unroll
    for (int i = 0; i < 6; i++) {
        int chunk = threadIdx.x + 256 * i;
        int row = chunk / 48, cc = chunk % 48;
        *(uint4*)(yact + ((size_t)(m0 + row)) * 384 + cc * 8) =
            *(const uint4*)&tile[row][cc * 8];
    }
}

extern "C" void kernel_launch(void* const* d_in, const int* in_sizes, int n_in,
                              void* d_out, int out_size, void* d_ws, size_t ws_size,
                              hipStream_t stream) {
    float* ws = (float*)d_ws;
    constexpr size_t S = (size_t)M * 384;
    float* xT   = ws;                          // x-branch [c][M]; reused as yT
    float* zT   = xT + S;                      // z [c][M]; reused as m1 (bf16 row)
    float* xinT = zT + S;                      // conv+silu [c][M]
    float* dtT  = xinT + S;                    // dt [d][M]; reused as yact (bf16 row)
    float* x1   = dtT + S;                     // x1 (row fp32)
    unsigned short* Brow = (unsigned short*)(x1 + S);                 // [M][16]
    unsigned short* Crow = Brow + (size_t)M * 16;
    float* part = (float*)(Crow + (size_t)M * 16);                    // [6][56][M]
    float* smalls = part + (size_t)6 * 56 * M;

    float* g1f  = smalls;        float* b1f  = g1f + 384;
    float* binf = b1f + 384;     float* cwf  = binf + 768;
    float* cbf  = cwf + 10368;   float* wxf  = cbf + 384;
    float* wdtf = wxf + 21504;   float* bdtf = wdtf + 9216;
    float* alogf= bdtf + 384;    float* dskf = alogf + 6144;
    float* ongf = dskf + 384;    float* onbf = ongf + 384;
    float* boutf= onbf + 384;    float* g2f  = boutf + 384;
    float* b2f_ = g2f + 384;     float* b1mf = b2f_ + 384;
    float* b2mf = b1mf + 384;
    unsigned short* WinT  = (unsigned short*)(b2mf + 384);
    unsigned short* WoutT = WinT + 294912;
    unsigned short* W1T   = WoutT + 147456;
    unsigned short* W2T   = W1T + 147456;

    float* yT = xT;
    unsigned short* yactb = (unsigned short*)dtT;
    unsigned short* m1b = (unsigned short*)zT;
    const unsigned short* g1p = (const unsigned short*)d_in[1];

    PrepTab tab;
    {
        tab.tsrc[0] = d_in[3];  tab.tdst[0] = WinT;  tab.tK[0] = 384; tab.tN[0] = 768;
        tab.tsrc[1] = d_in[14]; tab.tdst[1] = WoutT; tab.tK[1] = 384; tab.tN[1] = 384;
        tab.tsrc[2] = d_in[18]; tab.tdst[2] = W1T;   tab.tK[2] = 384; tab.tN[2] = 384;
        tab.tsrc[3] = d_in[20]; tab.tdst[3] = W2T;   tab.tK[3] = 384; tab.tN[3] = 384;
        int idxs[17] = {1, 2, 4, 5, 6, 7, 8, 9, 10, 11, 12, 13, 15, 16, 17, 19, 21};
        float* dsts[17] = {g1f, b1f, binf, cwf, cbf, wxf, wdtf, bdtf, alogf, dskf,
                           ongf, onbf, boutf, g2f, b2f_, b1mf, b2mf};
        int ns[17] = {384, 384, 768, 10368, 384, 21504, 9216, 384, 6144, 384,
                      384, 384, 384, 384, 384, 384, 384};
        int off = 0;
        for (int k = 0; k < 17; k++) {
            tab.csrc[k] = d_in[idxs[k]];
            tab.cdst[k] = dsts[k];
            tab.coff[k] = off;
            off += ns[k];
        }
        tab.coff[17] = off;
        prep_k<<<dim3(24, 12, 5), 256, 0, stream>>>(tab, g1p, off);
    }

    lngemm_k<768, 128, EPI_XZT, true><<<dim3(M / 128, 6), 256, 0, stream>>>(
        d_in[0], g1f, b1f, WinT, binf, xT, zT, nullptr, g1p);
    convT_k<<<dim3(M / 1024, DI), 256, 0, stream>>>(xT, cwf, cbf, xinT);
    dbc2_k<<<dim3(M / 64, 6), 256, 0, stream>>>(xinT, wxf, part);
    dbcfin_k<<<dim3(M / 64, 6), 256, 0, stream>>>(part, wdtf, bdtf, dtT, Brow, Crow);
    scan4_k<<<Bb * DI, 128, 0, stream>>>(dtT, xinT, Brow, Crow, alogf, dskf, yT);
    lnmulT_k<<<M / 32, 256, 0, stream>>>(yT, zT, ongf, onbf, yactb);
    gemm_mfma<384, 64, EPI_OUT><<<dim3(M / 128, 6), 256, 0, stream>>>(
        (const bf16*)yactb, WoutT, boutf, x1, nullptr, d_in[0], nullptr, g1p);
    lngemm_k<384, 64, EPI_GELU, false><<<dim3(M / 128, 6), 256, 0, stream>>>(
        x1, g2f, b2f_, W1T, b1mf, nullptr, nullptr, m1b, g1p);
    gemm_mfma<384, 64, EPI_FINAL><<<dim3(M / 128, 6), 256, 0, stream>>>(
        (const bf16*)m1b, W2T, b2mf, nullptr, x1, nullptr, d_out, g1p);
}

// Round 10
// 232.040 us; speedup vs baseline: 1.2087x; 1.2087x over previous
//
#include <hip/hip_runtime.h>
#include <hip/hip_bf16.h>

using bf16 = __hip_bfloat16;
#define DEV __device__ __forceinline__

typedef __attribute__((ext_vector_type(8))) short short8;
typedef __attribute__((ext_vector_type(8))) unsigned short ushort8;
typedef __attribute__((ext_vector_type(4))) float f32x4;

constexpr int Bb = 2, DD = 8, HH = 16, WW = 16;
constexpr int C = 384, DI = 384, DS = 16, RR = 24;
constexpr int L = DD * HH * WW;       // 2048
constexpr int M = Bb * L;             // 4096

DEV bf16 f2b(float v) { return __float2bfloat16(v); }
DEV unsigned short f2bu(float v) {
    bf16 t = __float2bfloat16(v);
    unsigned short u; __builtin_memcpy(&u, &t, 2); return u;
}
DEV float braw(unsigned short u) {
    unsigned int x = ((unsigned int)u) << 16;
    float f; __builtin_memcpy(&f, &x, 4); return f;
}
DEV bool isbf(const unsigned short* g1p) { return g1p[0] == 0x3F80; }

typedef const __attribute__((address_space(1))) unsigned int* gaddr_t;
typedef __attribute__((address_space(3))) unsigned int* laddr_t;
DEV void gload_lds16(const void* g, void* l) {
    __builtin_amdgcn_global_load_lds((gaddr_t)g, (laddr_t)l, 16, 0, 0);
}

DEV float wred64(float v) {
    #pragma unroll
    for (int off = 32; off > 0; off >>= 1) v += __shfl_xor(v, off, 64);
    return v;
}
DEV float siluf(float x) { return x / (1.0f + __expf(-x)); }
DEV float softplusf(float x) { return (x > 15.0f) ? x : log1pf(__expf(x)); }
DEV float gelu_tanh(float x) {
    const float k0 = 0.7978845608028654f;
    float u = k0 * (x + 0.044715f * x * x * x);
    float e = __expf(2.0f * u);
    float t = 1.0f - 2.0f / (e + 1.0f);
    return 0.5f * x * (1.0f + t);
}

// --------- merged prep: 4 weight transposes + 17 small cvts ---------------
struct PrepTab {
    const void* tsrc[4];
    unsigned short* tdst[4];
    int tK[4], tN[4];
    const void* csrc[17];
    float* cdst[17];
    int coff[18];
};
__global__ __launch_bounds__(256) void prep_k(PrepTab t,
                                              const unsigned short* __restrict__ g1p,
                                              int ctotal) {
    bool fl = isbf(g1p);
    int z = blockIdx.z;
    if (z < 4) {
        __shared__ unsigned short tt[32][33];
        int N = t.tN[z], K = t.tK[z];
        int n0 = blockIdx.x * 32, k0 = blockIdx.y * 32;
        if (n0 >= N || k0 >= K) return;
        const void* src = t.tsrc[z];
        unsigned short* dst = t.tdst[z];
        int tx = threadIdx.x & 31, ty = threadIdx.x >> 5;
        #pragma unroll
        for (int i = 0; i < 4; i++) {
            int k = k0 + ty + i * 8;
            unsigned short u;
            if (fl) u = ((const unsigned short*)src)[(size_t)k * N + n0 + tx];
            else    u = f2bu(((const float*)src)[(size_t)k * N + n0 + tx]);
            tt[ty + i * 8][tx] = u;
        }
        __syncthreads();
        #pragma unroll
        for (int i = 0; i < 4; i++) {
            int n = n0 + ty + i * 8;
            dst[(size_t)n * K + k0 + tx] = tt[tx][ty + i * 8];
        }
    } else {
        int i = (blockIdx.y * 24 + blockIdx.x) * 256 + threadIdx.x;
        if (i >= ctotal) return;
        int seg = 0;
        #pragma unroll
        for (int k = 1; k < 18; k++) seg += (i >= t.coff[k]) ? 1 : 0;
        int j = i - t.coff[seg];
        const void* s = t.csrc[seg];
        float v = fl ? braw(((const unsigned short*)s)[j]) : ((const float*)s)[j];
        t.cdst[seg][j] = v;
    }
}

// ---------- LayerNorm (token per wave) -> bf16 out ------------------------
template <bool RAWIN>
__global__ __launch_bounds__(256) void ln_k(const void* __restrict__ xr,
                                            const float* __restrict__ g,
                                            const float* __restrict__ b,
                                            bf16* __restrict__ out,
                                            const unsigned short* __restrict__ g1p) {
    bool fl = RAWIN ? isbf(g1p) : false;
    int wave = blockIdx.x * 4 + (threadIdx.x >> 6);
    int lane = threadIdx.x & 63;
    size_t base = (size_t)wave * C;
    float v[6];
    #pragma unroll
    for (int j = 0; j < 6; j++) {
        size_t idx = base + lane + 64 * j;
        if (RAWIN && fl) v[j] = braw(((const unsigned short*)xr)[idx]);
        else             v[j] = ((const float*)xr)[idx];
    }
    float s = 0.f;
    #pragma unroll
    for (int j = 0; j < 6; j++) s += v[j];
    s = wred64(s);
    float mean = s * (1.0f / C);
    float q = 0.f;
    #pragma unroll
    for (int j = 0; j < 6; j++) { float d = v[j] - mean; q += d * d; }
    q = wred64(q);
    float rstd = rsqrtf(q * (1.0f / C) + 1e-6f);
    #pragma unroll
    for (int j = 0; j < 6; j++) {
        int c = lane + 64 * j;
        out[base + c] = f2b((v[j] - mean) * rstd * g[c] + b[c]);
    }
}

// --------------- MFMA GEMM: bf16 A[M][384] x bf16 Bt[N][384] --------------
// tile 128m x TNn. TN=128: 4 waves 64x64. TN=64: 4 waves 32x64.
enum { EPI_XZT = 0, EPI_OUT = 1, EPI_GELU = 2, EPI_FINAL = 3 };

template <int N, int TN, int EPI>
__global__ __launch_bounds__(256) void gemm_mfma(const bf16* __restrict__ A,
                                                 const unsigned short* __restrict__ Bt,
                                                 const float* __restrict__ bias,
                                                 float* __restrict__ o0,
                                                 float* __restrict__ o1,
                                                 const float* __restrict__ auxf,
                                                 const void* __restrict__ auxraw,
                                                 void* __restrict__ obf,
                                                 const unsigned short* __restrict__ g1p) {
    __shared__ unsigned short Asb[128 * 32];
    __shared__ unsigned short Bsb[TN * 32];
    constexpr int MT = (TN == 128) ? 4 : 2;
    int tid = threadIdx.x;
    int m0 = blockIdx.x * 128, n0 = blockIdx.y * TN;
    int wid = tid >> 6, lane = tid & 63;
    int wm = (TN == 128) ? (wid >> 1) * 64 : wid * 32;
    int wn = (TN == 128) ? (wid & 1) * 64 : 0;
    int quad = lane >> 4, l15 = lane & 15;
    f32x4 acc[MT][4] = {};
    int srow = tid >> 2, sseg = (tid & 3) * 8;
    const unsigned short* Au = (const unsigned short*)A;
    for (int k0 = 0; k0 < 384; k0 += 32) {
        __syncthreads();
        gload_lds16(Au + (size_t)(m0 + srow) * 384 + k0 + sseg,
                    &Asb[srow * 32 + sseg]);
        gload_lds16(Au + (size_t)(m0 + 64 + srow) * 384 + k0 + sseg,
                    &Asb[(64 + srow) * 32 + sseg]);
        gload_lds16(Bt + (size_t)(n0 + srow) * 384 + k0 + sseg,
                    &Bsb[srow * 32 + sseg]);
        if constexpr (TN == 128)
            gload_lds16(Bt + (size_t)(n0 + 64 + srow) * 384 + k0 + sseg,
                        &Bsb[(64 + srow) * 32 + sseg]);
        __syncthreads();
        short8 af[MT], bfr[4];
        #pragma unroll
        for (int mt = 0; mt < MT; mt++)
            af[mt] = *(const short8*)&Asb[(wm + mt * 16 + l15) * 32 + quad * 8];
        #pragma unroll
        for (int nt = 0; nt < 4; nt++)
            bfr[nt] = *(const short8*)&Bsb[(wn + nt * 16 + l15) * 32 + quad * 8];
        #pragma unroll
        for (int mt = 0; mt < MT; mt++)
            #pragma unroll
            for (int nt = 0; nt < 4; nt++)
                acc[mt][nt] = __builtin_amdgcn_mfma_f32_16x16x32_bf16(
                    af[mt], bfr[nt], acc[mt][nt], 0, 0, 0);
    }
    bool fl = (EPI == EPI_FINAL || EPI == EPI_OUT) ? isbf(g1p) : false;
    #pragma unroll
    for (int mt = 0; mt < MT; mt++) {
        #pragma unroll
        for (int nt = 0; nt < 4; nt++) {
            int n = n0 + wn + nt * 16 + l15;
            int mb = m0 + wm + mt * 16 + quad * 4;
            float bi = bias[n];
            if constexpr (EPI == EPI_XZT) {
                f32x4 v = acc[mt][nt];
                v[0] += bi; v[1] += bi; v[2] += bi; v[3] += bi;
                float* dst = (n < 384) ? (o0 + (size_t)n * M + mb)
                                       : (o1 + (size_t)(n - 384) * M + mb);
                *(f32x4*)dst = v;
            } else {
                #pragma unroll
                for (int r = 0; r < 4; r++) {
                    int m = mb + r;
                    float v = acc[mt][nt][r] + bi;
                    if constexpr (EPI == EPI_OUT) {
                        float av;
                        if (fl) av = braw(((const unsigned short*)auxraw)[(size_t)m * 384 + n]);
                        else    av = ((const float*)auxraw)[(size_t)m * 384 + n];
                        o0[(size_t)m * 384 + n] = v + av;
                    } else if constexpr (EPI == EPI_GELU) {
                        ((bf16*)obf)[(size_t)m * 384 + n] = f2b(gelu_tanh(v));
                    } else {  // EPI_FINAL
                        float rr = v + auxf[(size_t)m * 384 + n];
                        if (fl) ((bf16*)obf)[(size_t)m * 384 + n] = f2b(rr);
                        else    ((float*)obf)[(size_t)m * 384 + n] = rr;
                    }
                }
            }
        }
    }
}

// --------- depthwise 3x3x3 conv + SiLU, 4 outputs per thread --------------
__global__ __launch_bounds__(256) void convT_k(const float* __restrict__ xT,
                                               const float* __restrict__ cw,
                                               const float* __restrict__ cb,
                                               float* __restrict__ xinT) {
    int c = blockIdx.y;
    int m0 = (blockIdx.x * 256 + threadIdx.x) * 4;
    int l = m0 & (L - 1);
    int d = l >> 8, h = (l >> 4) & 15, w0 = l & 15;
    const float* xc = xT + (size_t)c * M;
    const float* wc = cw + c * 27;
    float bias = cb[c];
    float acc[4] = {bias, bias, bias, bias};
    #pragma unroll
    for (int kd = -1; kd <= 1; kd++) {
        int dd = d + kd; if ((unsigned)dd >= 8u) continue;
        #pragma unroll
        for (int kh = -1; kh <= 1; kh++) {
            int hh = h + kh; if ((unsigned)hh >= 16u) continue;
            int mm = m0 + kd * 256 + kh * 16;
            float vv[6];
            vv[0] = (w0 == 0) ? 0.f : xc[mm - 1];
            float4 v14 = *(const float4*)(xc + mm);
            vv[1] = v14.x; vv[2] = v14.y; vv[3] = v14.z; vv[4] = v14.w;
            vv[5] = (w0 == 12) ? 0.f : xc[mm + 4];
            const float* wk = wc + (kd + 1) * 9 + (kh + 1) * 3;
            float wa = wk[0], wb = wk[1], wcc = wk[2];
            #pragma unroll
            for (int j = 0; j < 4; j++)
                acc[j] = fmaf(vv[j], wa, fmaf(vv[j + 1], wb, fmaf(vv[j + 2], wcc, acc[j])));
        }
    }
    float4 o = make_float4(siluf(acc[0]), siluf(acc[1]), siluf(acc[2]), siluf(acc[3]));
    *(float4*)(xinT + (size_t)c * M + m0) = o;
}

// ---- dbc split-K: partials part[kc][56][M] -------------------------------
__global__ __launch_bounds__(256) void dbc2_k(const float* __restrict__ xinT,
                                              const float* __restrict__ Wx,
                                              float* __restrict__ part) {
    __shared__ float As[16][64];
    __shared__ float Ws[16 * 56];
    int tid = threadIdx.x;
    int m0 = blockIdx.x * 64;
    int kc = blockIdx.y;
    int tm = tid & 63, grp = tid >> 6;
    int kk = tid >> 4, mc = (tid & 15) * 4;
    float acc[14] = {};
    for (int k0 = kc * 64; k0 < kc * 64 + 64; k0 += 16) {
        float4 av = *(const float4*)(xinT + (size_t)(k0 + kk) * M + m0 + mc);
        __syncthreads();
        *(float4*)&As[kk][mc] = av;
        for (int idx = tid; idx < 16 * 56; idx += 256)
            Ws[idx] = Wx[k0 * 56 + idx];
        __syncthreads();
        #pragma unroll
        for (int k = 0; k < 16; k++) {
            float a = As[k][tm];
            #pragma unroll
            for (int jj = 0; jj < 14; jj++)
                acc[jj] = fmaf(a, Ws[k * 56 + grp * 14 + jj], acc[jj]);
        }
    }
    int m = m0 + tm;
    #pragma unroll
    for (int jj = 0; jj < 14; jj++) {
        int col = grp * 14 + jj;
        part[((size_t)kc * 56 + col) * M + m] = acc[jj];
    }
}

// ---- fused: reduce partials + write B/C + dtT = softplus(dtr @ Wdt) ------
// grid (M/64, 6), block 256. Block y covers n in [64y, 64y+64).
__global__ __launch_bounds__(256) void dbcfin_k(const float* __restrict__ part,
                                                const float* __restrict__ Wdt,
                                                const float* __restrict__ bdt,
                                                float* __restrict__ dtT,
                                                unsigned short* __restrict__ Brow,
                                                unsigned short* __restrict__ Crow) {
    __shared__ float dtr[24][64];
    int tid = threadIdx.x;
    int m0 = blockIdx.x * 64;
    int ng = blockIdx.y;
    for (int i = tid; i < 24 * 64; i += 256) {
        int col = i >> 6, mm = i & 63;
        float s = 0.f;
        #pragma unroll
        for (int kc = 0; kc < 6; kc++)
            s += part[((size_t)kc * 56 + col) * M + m0 + mm];
        dtr[col][mm] = s;
    }
    if (ng == 0) {
        for (int i = tid; i < 32 * 64; i += 256) {
            int col = 24 + (i >> 6), mm = i & 63;
            float s = 0.f;
            #pragma unroll
            for (int kc = 0; kc < 6; kc++)
                s += part[((size_t)kc * 56 + col) * M + m0 + mm];
            int m = m0 + mm;
            if (col < 40) Brow[(size_t)m * 16 + col - 24] = f2bu(s);
            else          Crow[(size_t)m * 16 + col - 40] = f2bu(s);
        }
    }
    __syncthreads();
    int mm = tid & 63, nq = tid >> 6;
    #pragma unroll 4
    for (int nj = 0; nj < 16; nj++) {
        int n = ng * 64 + nq * 16 + nj;
        float acc = bdt[n];
        #pragma unroll
        for (int j = 0; j < 24; j++)
            acc = fmaf(dtr[j][mm], Wdt[j * 384 + n], acc);
        dtT[(size_t)n * M + m0 + mm] = softplusf(acc);
    }
}

// ------------- scan4: LDS-staged, padded, register-state scan -------------
__global__ __launch_bounds__(128) void scan4_k(const float* __restrict__ dtT,
                                               const float* __restrict__ xinT,
                                               const unsigned short* __restrict__ Brow,
                                               const unsigned short* __restrict__ Crow,
                                               const float* __restrict__ alog,
                                               const float* __restrict__ dsk,
                                               float* __restrict__ yT) {
    __shared__ float dt_s[2112], x_s[2112];
    __shared__ float ypart[2 * 2112];
    int bi = blockIdx.x;
    int b = bi / DI, d = bi % DI;
    int wave = threadIdx.x >> 6, lane = threadIdx.x & 63;
    int s0 = wave * 8;
    float Aneg[8];
    #pragma unroll
    for (int ss = 0; ss < 8; ss++) Aneg[ss] = -__expf(alog[d * DS + s0 + ss]);
    const float* dtp = dtT + (size_t)d * M + b * L;
    const float* xp  = xinT + (size_t)d * M + b * L;
    #pragma unroll
    for (int i = 0; i < 4; i++) {
        int t4 = (threadIdx.x + i * 128) * 4;
        float4 dv = *(const float4*)(dtp + t4);
        float4 xv = *(const float4*)(xp + t4);
        int base = t4 + (t4 >> 5);
        dt_s[base + 0] = dv.x; dt_s[base + 1] = dv.y;
        dt_s[base + 2] = dv.z; dt_s[base + 3] = dv.w;
        x_s[base + 0] = xv.x; x_s[base + 1] = xv.y;
        x_s[base + 2] = xv.z; x_s[base + 3] = xv.w;
    }
    __syncthreads();
    const unsigned short* Bp = Brow + ((size_t)b * L) * 16 + s0;
    const unsigned short* Cp = Crow + ((size_t)b * L) * 16 + s0;
    int tbase = lane * 32;
    int pbase = lane * 33;
    float Ap[8], Bg[8];
    #pragma unroll
    for (int ss = 0; ss < 8; ss++) { Ap[ss] = 1.f; Bg[ss] = 0.f; }
    #pragma unroll 4
    for (int j = 0; j < 32; j++) {
        float dtv = dt_s[pbase + j];
        float dxv = dtv * x_s[pbase + j];
        ushort8 bu = *(const ushort8*)(Bp + (size_t)(tbase + j) * 16);
        #pragma unroll
        for (int ss = 0; ss < 8; ss++) {
            float dA = __expf(dtv * Aneg[ss]);
            Bg[ss] = fmaf(dA, Bg[ss], dxv * braw(bu[ss]));
            Ap[ss] *= dA;
        }
    }
    float carry[8];
    #pragma unroll
    for (int ss = 0; ss < 8; ss++) {
        float a = Ap[ss], bb = Bg[ss];
        #pragma unroll
        for (int off = 1; off < 64; off <<= 1) {
            float ap = __shfl_up(a, off, 64);
            float bp = __shfl_up(bb, off, 64);
            if (lane >= off) { bb = fmaf(a, bp, bb); a *= ap; }
        }
        float c = __shfl_up(bb, 1, 64);
        carry[ss] = (lane == 0) ? 0.f : c;
    }
    float* ypw = ypart + wave * 2112;
    float h[8];
    #pragma unroll
    for (int ss = 0; ss < 8; ss++) h[ss] = carry[ss];
    #pragma unroll 4
    for (int j = 0; j < 32; j++) {
        float dtv = dt_s[pbase + j];
        float dxv = dtv * x_s[pbase + j];
        size_t toff = (size_t)(tbase + j) * 16;
        ushort8 bu = *(const ushort8*)(Bp + toff);
        ushort8 cu = *(const ushort8*)(Cp + toff);
        float acc = 0.f;
        #pragma unroll
        for (int ss = 0; ss < 8; ss++) {
            float dA = __expf(dtv * Aneg[ss]);
            h[ss] = fmaf(dA, h[ss], dxv * braw(bu[ss]));
            acc = fmaf(h[ss], braw(cu[ss]), acc);
        }
        ypw[pbase + j] = acc;
    }
    __syncthreads();
    float Dv = dsk[d];
    float* yp = yT + (size_t)d * M + b * L;
    #pragma unroll
    for (int i = 0; i < 16; i++) {
        int t = threadIdx.x + 128 * i;
        int ti = t + (t >> 5);
        yp[t] = fmaf(x_s[ti], Dv, ypart[ti] + ypart[2112 + ti]);
    }
}

// ---- yact(row bf16) = LN_over_d(yT) * silu(zT), coalesced two-pass -------
__global__ __launch_bounds__(256) void lnmulT_k(const float* __restrict__ yT,
                                                const float* __restrict__ zT,
                                                const float* __restrict__ g,
                                                const float* __restrict__ b,
                                                unsigned short* __restrict__ yact) {
    __shared__ float rs1[8][32], rs2[8][32];
    __shared__ float meanb[32], rstdb[32];
    __shared__ unsigned short tile[32][392];
    int moff = threadIdx.x & 31;
    int dsub = threadIdx.x >> 5;
    int m0 = blockIdx.x * 32;
    size_t mg = m0 + moff;
    float s1 = 0.f, s2 = 0.f;
    #pragma unroll 8
    for (int j = 0; j < 48; j++) {
        int d = dsub + 8 * j;
        float v = yT[(size_t)d * M + mg];
        s1 += v; s2 += v * v;
    }
    rs1[dsub][moff] = s1;
    rs2[dsub][moff] = s2;
    __syncthreads();
    if (threadIdx.x < 32) {
        float a1 = 0.f, a2 = 0.f;
        #pragma unroll
        for (int ss = 0; ss < 8; ss++) { a1 += rs1[ss][threadIdx.x]; a2 += rs2[ss][threadIdx.x]; }
        float mean = a1 * (1.0f / DI);
        float var = a2 * (1.0f / DI) - mean * mean;
        meanb[threadIdx.x] = mean;
        rstdb[threadIdx.x] = rsqrtf(var + 1e-6f);
    }
    __syncthreads();
    float mean = meanb[moff], rstd = rstdb[moff];
    #pragma unroll 8
    for (int j = 0; j < 48; j++) {
        int d = dsub + 8 * j;
        float v = yT[(size_t)d * M + mg];
        float ln = (v - mean) * rstd * g[d] + b[d];
        float zv = zT[(size_t)d * M + mg];
        tile[moff][d] = f2bu(ln * siluf(zv));
    }
    __syncthreads();
    #pragma unroll
    for (int i = 0; i < 6; i++) {
        int chunk = threadIdx.x + 256 * i;
        int row = chunk / 48, cc = chunk % 48;
        *(uint4*)(yact + ((size_t)(m0 + row)) * 384 + cc * 8) =
            *(const uint4*)&tile[row][cc * 8];
    }
}

extern "C" void kernel_launch(void* const* d_in, const int* in_sizes, int n_in,
                              void* d_out, int out_size, void* d_ws, size_t ws_size,
                              hipStream_t stream) {
    float* ws = (float*)d_ws;
    constexpr size_t S = (size_t)M * 384;
    bf16*  hb   = (bf16*)ws;                   // LN out bf16 (row); reused as h2
    float* xT   = ws + S / 2;                  // x-branch [c][M]; reused as yT
    float* zT   = xT + S;                      // z [c][M]; reused as m1 (bf16 row)
    float* xinT = zT + S;                      // conv+silu [c][M]
    float* dtT  = xinT + S;                    // dt [d][M]; reused as yact (bf16 row)
    float* x1   = dtT + S;                     // x1 (row fp32)
    unsigned short* Brow = (unsigned short*)(x1 + S);                 // [M][16]
    unsigned short* Crow = Brow + (size_t)M * 16;
    float* part = (float*)(Crow + (size_t)M * 16);                    // [6][56][M]
    float* smalls = part + (size_t)6 * 56 * M;

    float* g1f  = smalls;        float* b1f  = g1f + 384;
    float* binf = b1f + 384;     float* cwf  = binf + 768;
    float* cbf  = cwf + 10368;   float* wxf  = cbf + 384;
    float* wdtf = wxf + 21504;   float* bdtf = wdtf + 9216;
    float* alogf= bdtf + 384;    float* dskf = alogf + 6144;
    float* ongf = dskf + 384;    float* onbf = ongf + 384;
    float* boutf= onbf + 384;    float* g2f  = boutf + 384;
    float* b2f_ = g2f + 384;     float* b1mf = b2f_ + 384;
    float* b2mf = b1mf + 384;
    unsigned short* WinT  = (unsigned short*)(b2mf + 384);
    unsigned short* WoutT = WinT + 294912;
    unsigned short* W1T   = WoutT + 147456;
    unsigned short* W2T   = W1T + 147456;

    float* yT = xT;
    bf16* h2b = hb;
    unsigned short* yactb = (unsigned short*)dtT;
    unsigned short* m1b = (unsigned short*)zT;
    const unsigned short* g1p = (const unsigned short*)d_in[1];

    PrepTab tab;
    {
        tab.tsrc[0] = d_in[3];  tab.tdst[0] = WinT;  tab.tK[0] = 384; tab.tN[0] = 768;
        tab.tsrc[1] = d_in[14]; tab.tdst[1] = WoutT; tab.tK[1] = 384; tab.tN[1] = 384;
        tab.tsrc[2] = d_in[18]; tab.tdst[2] = W1T;   tab.tK[2] = 384; tab.tN[2] = 384;
        tab.tsrc[3] = d_in[20]; tab.tdst[3] = W2T;   tab.tK[3] = 384; tab.tN[3] = 384;
        int idxs[17] = {1, 2, 4, 5, 6, 7, 8, 9, 10, 11, 12, 13, 15, 16, 17, 19, 21};
        float* dsts[17] = {g1f, b1f, binf, cwf, cbf, wxf, wdtf, bdtf, alogf, dskf,
                           ongf, onbf, boutf, g2f, b2f_, b1mf, b2mf};
        int ns[17] = {384, 384, 768, 10368, 384, 21504, 9216, 384, 6144, 384,
                      384, 384, 384, 384, 384, 384, 384};
        int off = 0;
        for (int k = 0; k < 17; k++) {
            tab.csrc[k] = d_in[idxs[k]];
            tab.cdst[k] = dsts[k];
            tab.coff[k] = off;
            off += ns[k];
        }
        tab.coff[17] = off;
        prep_k<<<dim3(24, 12, 5), 256, 0, stream>>>(tab, g1p, off);
    }

    ln_k<true><<<M / 4, 256, 0, stream>>>(d_in[0], g1f, b1f, hb, g1p);
    gemm_mfma<768, 128, EPI_XZT><<<dim3(M / 128, 6), 256, 0, stream>>>(
        hb, WinT, binf, xT, zT, nullptr, nullptr, nullptr, g1p);
    convT_k<<<dim3(M / 1024, DI), 256, 0, stream>>>(xT, cwf, cbf, xinT);
    dbc2_k<<<dim3(M / 64, 6), 256, 0, stream>>>(xinT, wxf, part);
    dbcfin_k<<<dim3(M / 64, 6), 256, 0, stream>>>(part, wdtf, bdtf, dtT, Brow, Crow);
    scan4_k<<<Bb * DI, 128, 0, stream>>>(dtT, xinT, Brow, Crow, alogf, dskf, yT);
    lnmulT_k<<<M / 32, 256, 0, stream>>>(yT, zT, ongf, onbf, yactb);
    gemm_mfma<384, 64, EPI_OUT><<<dim3(M / 128, 6), 256, 0, stream>>>(
        (const bf16*)yactb, WoutT, boutf, x1, nullptr, nullptr, d_in[0], nullptr, g1p);
    ln_k<false><<<M / 4, 256, 0, stream>>>(x1, g2f, b2f_, h2b, g1p);
    gemm_mfma<384, 64, EPI_GELU><<<dim3(M / 128, 6), 256, 0, stream>>>(
        h2b, W1T, b1mf, nullptr, nullptr, nullptr, nullptr, m1b, g1p);
    gemm_mfma<384, 64, EPI_FINAL><<<dim3(M / 128, 6), 256, 0, stream>>>(
        (const bf16*)m1b, W2T, b2mf, nullptr, nullptr, x1, nullptr, d_out, g1p);
}